// Round 3
// baseline (359.811 us; speedup 1.0000x reference)
//
#include <hip/hip_runtime.h>
#include <math.h>

#define B 128
#define T 2048
#define H 200
#define G4 800   // 4*H
#define KP 224   // Uab row stride (bf16), K padded to multiple of 32

typedef short short8 __attribute__((ext_vector_type(8)));
typedef float floatx4 __attribute__((ext_vector_type(4)));

__device__ __forceinline__ unsigned short f2bf(float x) {
    unsigned u = __float_as_uint(x);
    return (unsigned short)((u + 0x7fffu + ((u >> 16) & 1u)) >> 16);
}
// pack two floats -> two bf16 (round-nearest-away) in 3 VALU ops
__device__ __forceinline__ unsigned pk2(float a, float b) {
    return __builtin_amdgcn_perm(__float_as_uint(b) + 0x8000u,
                                 __float_as_uint(a) + 0x8000u, 0x07060302u);
}
// tanh(x) = 1 - 2/(exp(2x)+1), hw exp2 + rcp (~1e-6 rel err)
__device__ __forceinline__ float ftanh(float x) {
    float e = __builtin_amdgcn_exp2f(x * 2.885390081777927f);
    float r = __builtin_amdgcn_rcpf(e + 1.f);
    return fmaf(-2.f, r, 1.f);
}
__device__ __forceinline__ float sigm(float x) { return 1.f / (1.f + expf(-x)); }

// load 8 consecutive f32 -> bf16 short8 B-fragment. NO union (round-2's union
// defeated SROA -> 390 MB scratch traffic); __builtin_bit_cast stays in registers.
__device__ __forceinline__ short8 ld_bfrag(const float* __restrict__ p) {
    float4 a = *(const float4*)p;
    float4 c = *(const float4*)(p + 4);
    uint4 u;
    u.x = pk2(a.x, a.y);
    u.y = pk2(a.z, a.w);
    u.z = pk2(c.x, c.y);
    u.w = pk2(c.z, c.w);
    return __builtin_bit_cast(short8, u);
}

// ---------------- prep_all ----------------
// blocks 0..255    : Uab row (bf16, zero-padded [256][224])
// blocks 256..455  : W_ihT[k][j] = W_ih[j][1+k]
// blocks 456..655  : W_hhT[k][j] = W_hh[j][k]
// block  656       : wx[j] = W_ih[j][0]
// blocks 657..784  : qb[b][h] = h0[b] @ Wa.T + ba + bua   (float4 dot)
// blocks 785..984  : W1T[k][j] = W1[j][k]   (k<200, j<100)
// blocks 985..1084 : W2T[k][j] = W2[j][k]   (k<100, j<50)
__global__ __launch_bounds__(256) void prep_all(const float* __restrict__ Ua,
                                                const float* __restrict__ Wa,
                                                const float* __restrict__ ba,
                                                const float* __restrict__ bua,
                                                const float* __restrict__ h0,
                                                const float* __restrict__ W_ih,
                                                const float* __restrict__ W_hh,
                                                const float* __restrict__ W1,
                                                const float* __restrict__ W2,
                                                unsigned short* __restrict__ Uab,
                                                float* __restrict__ WihT,
                                                float* __restrict__ WhhT,
                                                float* __restrict__ wx,
                                                float* __restrict__ qb,
                                                float* __restrict__ W1T,
                                                float* __restrict__ W2T) {
    __shared__ __align__(16) float qs[H];
    int bx = blockIdx.x, tid = threadIdx.x;
    if (bx < 256) {
        if (tid < KP) {
            float v = (bx < H && tid < H) ? Ua[bx * H + tid] : 0.f;
            Uab[bx * KP + tid] = f2bf(v);
        }
    } else if (bx < 456) {
        int k = bx - 256;
        for (int j = tid; j < G4; j += 256) WihT[k * G4 + j] = W_ih[(size_t)j * (H + 1) + 1 + k];
    } else if (bx < 656) {
        int k = bx - 456;
        for (int j = tid; j < G4; j += 256) WhhT[k * G4 + j] = W_hh[(size_t)j * H + k];
    } else if (bx == 656) {
        for (int j = tid; j < G4; j += 256) wx[j] = W_ih[(size_t)j * (H + 1)];
    } else if (bx < 785) {
        int b = bx - 657;
        if (tid < H) qs[tid] = h0[b * H + tid];
        __syncthreads();
        if (tid < H) {
            float a = ba[tid] + bua[tid];
            const float4* w  = (const float4*)(Wa + tid * H);
            const float4* qv = (const float4*)qs;
            #pragma unroll 8
            for (int k = 0; k < 50; k++) {
                float4 wv = w[k], q4 = qv[k];
                a = fmaf(wv.x, q4.x, a);
                a = fmaf(wv.y, q4.y, a);
                a = fmaf(wv.z, q4.z, a);
                a = fmaf(wv.w, q4.w, a);
            }
            qb[b * H + tid] = a;
        }
    } else if (bx < 985) {
        int k = bx - 785;
        if (tid < 100) W1T[k * 100 + tid] = W1[tid * H + k];
    } else {
        int k = bx - 985;
        if (tid < 50) W2T[k * 50 + tid] = W2[tid * 100 + k];
    }
}

// ---------------- scores + bounded-softmax + context (no LDS staging) ----------------
// Grid: 4096 = (b, 1/32 of T), 64 t-rows per block. B-fragments are loaded straight
// from global enc (f32) and converted in-register; first wave misses HBM, the rest
// hit L2 (tile = 51 KB). Uab k-pad columns are zero, so B garbage at k>=200 is
// annihilated by the A operand; q>0 lanes at ks==6 are zeroed (also avoids OOB at
// the very end of enc). No stage barriers, no vmcnt(0) drain.

template<int NM>
__device__ __forceinline__ void mig_scores(const unsigned short* __restrict__ Uab,
                                           const float* __restrict__ ebase,
                                           const float* s_va, const float* s_qb,
                                           int m0, int r, int q, float p[4]) {
    short8 af[NM][7];
    #pragma unroll
    for (int m = 0; m < NM; m++)
        #pragma unroll
        for (int ks = 0; ks < 7; ks++)
            af[m][ks] = *(const short8*)(Uab + ((m0 + m) * 16 + r) * KP + ks * 32 + q * 8);
    #pragma unroll
    for (int nt = 0; nt < 4; nt++) {
        const float* rowp = ebase + (nt * 16 + r) * H;
        floatx4 C[NM];
        #pragma unroll
        for (int m = 0; m < NM; m++) C[m] = (floatx4){0.f, 0.f, 0.f, 0.f};
        #pragma unroll
        for (int ks = 0; ks < 7; ks++) {
            short8 bf;
            if (ks < 6) {
                bf = ld_bfrag(rowp + ks * 32 + q * 8);
            } else if (q == 0) {
                bf = ld_bfrag(rowp + 192);
            } else {
                short8 z = {0, 0, 0, 0, 0, 0, 0, 0};
                bf = z;
            }
            #pragma unroll
            for (int m = 0; m < NM; m++)
                C[m] = __builtin_amdgcn_mfma_f32_16x16x32_bf16(af[m][ks], bf, C[m], 0, 0, 0);
        }
        float pp = 0.f;
        #pragma unroll
        for (int m = 0; m < NM; m++)
            #pragma unroll
            for (int g = 0; g < 4; g++) {
                int h = (m0 + m) * 16 + q * 4 + g;
                pp += s_va[h] * ftanh(s_qb[h] + C[m][g]);
            }
        p[nt] += pp;
    }
}

__global__ __launch_bounds__(256, 4) void scores_ctx(const float* __restrict__ enc,
                                                     const unsigned short* __restrict__ Uab,
                                                     const float* __restrict__ qb,
                                                     const float* __restrict__ Va,
                                                     const float* __restrict__ bva,
                                                     float* __restrict__ ctx_raw,
                                                     float* __restrict__ lsum) {
    __shared__ float part[4][64];
    __shared__ float s_qb[256];
    __shared__ float s_va[256];
    __shared__ float wlds[64];

    int bx  = blockIdx.x;
    int b   = bx >> 5;
    int t0  = (bx & 31) * 64;
    int tid = threadIdx.x, w = tid >> 6, lane = tid & 63, r = lane & 15, q = lane >> 4;

    s_qb[tid] = (tid < H) ? qb[b * H + tid] : 0.f;
    s_va[tid] = (tid < H) ? Va[tid] : 0.f;
    float bv = bva[0];
    __syncthreads();

    float bound = 0.f;   // sum|Va| + |bva| (wave 0)
    if (tid < 64) {
        float a = fabsf(s_va[tid]) + fabsf(s_va[tid + 64]) +
                  fabsf(s_va[tid + 128]) + fabsf(s_va[tid + 192]);
        #pragma unroll
        for (int d = 1; d < 64; d <<= 1) a += __shfl_xor(a, d);
        bound = a + fabsf(bv);
    }

    const float* ebase = enc + (size_t)(b * T + t0) * H;   // [64][200] f32 tile
    float p[4] = {0.f, 0.f, 0.f, 0.f};
    // 13 m-tiles (13*16=208 >= 200): wave0 {0..3}, wave1 {4..6}, wave2 {7..9}, wave3 {10..12}
    if (w == 0) {
        mig_scores<2>(Uab, ebase, s_va, s_qb, 0, r, q, p);
        mig_scores<2>(Uab, ebase, s_va, s_qb, 2, r, q, p);
    } else {
        int mbase = 1 + 3 * w;
        mig_scores<2>(Uab, ebase, s_va, s_qb, mbase, r, q, p);
        mig_scores<1>(Uab, ebase, s_va, s_qb, mbase + 2, r, q, p);
    }

    #pragma unroll
    for (int nt = 0; nt < 4; nt++) {
        float pp = p[nt];
        pp += __shfl_xor(pp, 16);
        pp += __shfl_xor(pp, 32);
        if (q == 0) part[w][nt * 16 + r] = pp;
    }
    __syncthreads();

    float lacc = 0.f;
    if (tid < 64) {   // wave 0: score -> bounded-softmax weight
        float s  = part[0][tid] + part[1][tid] + part[2][tid] + part[3][tid] + bv;
        float we = __builtin_amdgcn_exp2f((s - bound) * 1.4426950408889634f);
        wlds[tid] = we;
        #pragma unroll
        for (int d = 1; d < 64; d <<= 1) we += __shfl_xor(we, d);
        lacc = we;
    }
    __syncthreads();

    if (tid < H) {   // ctx[h] += sum_t w[t]*enc[t,h]; coalesced per-t, L2-hot tile
        float a0 = 0.f, a1 = 0.f, a2 = 0.f, a3 = 0.f;
        #pragma unroll
        for (int t = 0; t < 64; t += 4) {
            a0 = fmaf(wlds[t],     ebase[(t    ) * H + tid], a0);
            a1 = fmaf(wlds[t + 1], ebase[(t + 1) * H + tid], a1);
            a2 = fmaf(wlds[t + 2], ebase[(t + 2) * H + tid], a2);
            a3 = fmaf(wlds[t + 3], ebase[(t + 3) * H + tid], a3);
        }
        atomicAdd(&ctx_raw[b * H + tid], (a0 + a1) + (a2 + a3));
    }
    if (tid == 0) atomicAdd(&lsum[b], lacc);
}

// ---------------- decoder (fused gc prologue + 5 steps), 512 threads ----------------
__global__ __launch_bounds__(512) void decoder2(const float* __restrict__ x,
                                                const float* __restrict__ c0,
                                                const float* __restrict__ ctx_raw,
                                                const float* __restrict__ lsum,
                                                const float* __restrict__ h0,
                                                const float* __restrict__ WihT,
                                                const float* __restrict__ WhhT,
                                                const float* __restrict__ b_ih,
                                                const float* __restrict__ b_hh,
                                                const float* __restrict__ wx,
                                                const float* __restrict__ W1T,
                                                const float* __restrict__ b1,
                                                const float* __restrict__ W2T,
                                                const float* __restrict__ b2,
                                                const float* __restrict__ W3,
                                                const float* __restrict__ b3,
                                                float* __restrict__ out) {
    __shared__ float s_gc[G4];
    __shared__ float s_wx[G4];
    __shared__ float s_ctx[H];
    __shared__ float s_q[H];
    __shared__ float s_out[H];
    __shared__ float s_o1[100];
    __shared__ float s_o2[50];
    __shared__ float s_w3[64];
    __shared__ float s_x;
    int b = blockIdx.x, tid = threadIdx.x;

    if (tid < H) {
        float invl = 1.f / lsum[b];
        s_ctx[tid] = ctx_raw[b * H + tid] * invl;
        s_q[tid]   = h0[b * H + tid];
    }
    s_wx[tid] = wx[tid];
    if (tid < G4 - 512) s_wx[512 + tid] = wx[512 + tid];
    if (tid < 64) s_w3[tid] = (tid < 50) ? W3[tid] : 0.f;
    if (tid == 0) s_x = x[b];
    float b3v = b3[0];
    __syncthreads();

    // gc[j] = b_ih+b_hh + ctx.Wih[:,1:] + q.Whh   (two j per thread)
    {
        int j0 = tid;
        int j1 = 512 + ((tid < 288) ? tid : 287);
        float a0 = b_ih[j0] + b_hh[j0];
        float a1 = b_ih[j1] + b_hh[j1];
        #pragma unroll 4
        for (int k = 0; k < H; k++) {
            float cv = s_ctx[k], qv = s_q[k];
            a0 = fmaf(cv, WihT[k * G4 + j0], a0);
            a0 = fmaf(qv, WhhT[k * G4 + j0], a0);
            a1 = fmaf(cv, WihT[k * G4 + j1], a1);
            a1 = fmaf(qv, WhhT[k * G4 + j1], a1);
        }
        s_gc[j0] = a0;
        if (tid < 288) s_gc[512 + tid] = a1;
    }
    float cprev = (tid < H) ? c0[b * H + tid] : 0.f;
    __syncthreads();

    for (int s = 0; s < 5; s++) {
        float xv = s_x;
        if (tid < H) {
            float ig = s_gc[tid]         + xv * s_wx[tid];
            float fg = s_gc[H + tid]     + xv * s_wx[H + tid];
            float gg = s_gc[2 * H + tid] + xv * s_wx[2 * H + tid];
            float og = s_gc[3 * H + tid] + xv * s_wx[3 * H + tid];
            float c  = sigm(fg) * cprev + sigm(ig) * tanhf(gg);
            float hn = sigm(og) * tanhf(c);
            s_out[tid] = fmaxf(hn, 0.f);
        }
        __syncthreads();
        if (tid < 400) {   // W1: 4 lanes per output, k split 4x50
            int j = tid >> 2, q4 = tid & 3;
            float a = 0.f;
            const float* wp = W1T + (q4 * 50) * 100 + j;
            const float* op = s_out + q4 * 50;
            #pragma unroll 10
            for (int k = 0; k < 50; k++) a = fmaf(wp[k * 100], op[k], a);
            a += __shfl_xor(a, 1);
            a += __shfl_xor(a, 2);
            if (q4 == 0) s_o1[j] = fmaxf(a + b1[j], 0.f);
        }
        __syncthreads();
        if (tid < 200) {   // W2: 4 lanes per output, k split 4x25
            int j = tid >> 2, q4 = tid & 3;
            float a = 0.f;
            const float* wp = W2T + (q4 * 25) * 50 + j;
            const float* op = s_o1 + q4 * 25;
            #pragma unroll 5
            for (int k = 0; k < 25; k++) a = fmaf(wp[k * 50], op[k], a);
            a += __shfl_xor(a, 1);
            a += __shfl_xor(a, 2);
            if (q4 == 0) s_o2[j] = fmaxf(a + b2[j], 0.f);
        }
        __syncthreads();
        if (tid < 64) {   // W3: wave reduce
            float a = (tid < 50) ? s_w3[tid] * s_o2[tid] : 0.f;
            #pragma unroll
            for (int d = 1; d < 64; d <<= 1) a += __shfl_xor(a, d);
            if (tid == 0) {
                float y = a + b3v;
                out[b * 5 + s] = y;
                s_x = y;
            }
        }
        __syncthreads();
    }
}

// ---------------- launch ----------------
extern "C" void kernel_launch(void* const* d_in, const int* in_sizes, int n_in,
                              void* d_out, int out_size, void* d_ws, size_t ws_size,
                              hipStream_t stream) {
    (void)in_sizes; (void)n_in; (void)out_size; (void)ws_size;
    const float* x    = (const float*)d_in[0];
    const float* h0   = (const float*)d_in[1];
    const float* c0   = (const float*)d_in[2];
    const float* enc  = (const float*)d_in[3];
    const float* Wa   = (const float*)d_in[4];
    const float* ba   = (const float*)d_in[5];
    const float* Ua   = (const float*)d_in[6];
    const float* bua  = (const float*)d_in[7];
    const float* Va   = (const float*)d_in[8];
    const float* bva  = (const float*)d_in[9];
    const float* W_ih = (const float*)d_in[10];
    const float* W_hh = (const float*)d_in[11];
    const float* b_ih = (const float*)d_in[12];
    const float* b_hh = (const float*)d_in[13];
    const float* W1   = (const float*)d_in[14];
    const float* b1   = (const float*)d_in[15];
    const float* W2   = (const float*)d_in[16];
    const float* b2   = (const float*)d_in[17];
    const float* W3   = (const float*)d_in[18];
    const float* b3   = (const float*)d_in[19];
    float* out = (float*)d_out;

    char* ws = (char*)d_ws;
    unsigned short* Uab = (unsigned short*)(ws);   // 114688
    float* WihT    = (float*)(ws + 114688);        // 640000
    float* WhhT    = (float*)(ws + 754688);        // 640000
    float* wx      = (float*)(ws + 1394688);       // 3200
    float* qb      = (float*)(ws + 1397888);       // 102400
    float* W1T     = (float*)(ws + 1500288);       // 80000
    float* W2T     = (float*)(ws + 1580288);       // 20000
    float* ctx_raw = (float*)(ws + 1600288);       // 102400
    float* lsum    = (float*)(ws + 1702688);       // 512

    hipMemsetAsync(ws + 1600288, 0, 102912, stream);   // ctx_raw + lsum
    prep_all<<<dim3(1085), 256, 0, stream>>>(Ua, Wa, ba, bua, h0, W_ih, W_hh, W1, W2,
                                             Uab, WihT, WhhT, wx, qb, W1T, W2T);
    scores_ctx<<<dim3(4096), 256, 0, stream>>>(enc, Uab, qb, Va, bva, ctx_raw, lsum);
    decoder2<<<dim3(B), 512, 0, stream>>>(x, c0, ctx_raw, lsum, h0, WihT, WhhT,
                                          b_ih, b_hh, wx, W1T, b1, W2T, b2, W3, b3, out);
}

// Round 4
// 198.769 us; speedup vs baseline: 1.8102x; 1.8102x over previous
//
#include <hip/hip_runtime.h>
#include <math.h>

#define B 128
#define T 2048
#define H 200
#define G4 800   // 4*H
#define KP 224   // Uab row stride (bf16), K padded to multiple of 32
#define ROWS 32  // t-rows per tile
#define NTILE 4  // tiles per block (chunk = 128 rows)
#define TFLOAT (ROWS * H)   // 6400 floats per tile

typedef short short8 __attribute__((ext_vector_type(8)));
typedef float floatx4 __attribute__((ext_vector_type(4)));

__device__ __forceinline__ unsigned short f2bf(float x) {
    unsigned u = __float_as_uint(x);
    return (unsigned short)((u + 0x7fffu + ((u >> 16) & 1u)) >> 16);
}
// pack two floats -> two bf16 (round-nearest-away) in 3 VALU ops
__device__ __forceinline__ unsigned pk2(float a, float b) {
    return __builtin_amdgcn_perm(__float_as_uint(b) + 0x8000u,
                                 __float_as_uint(a) + 0x8000u, 0x07060302u);
}
// tanh(x) = 1 - 2/(exp(2x)+1), hw exp2 + rcp (~1e-6 rel err)
__device__ __forceinline__ float ftanh(float x) {
    float e = __builtin_amdgcn_exp2f(x * 2.885390081777927f);
    float r = __builtin_amdgcn_rcpf(e + 1.f);
    return fmaf(-2.f, r, 1.f);
}
__device__ __forceinline__ float sigm(float x) { return 1.f / (1.f + expf(-x)); }

// 8 consecutive f32 (LDS) -> bf16 short8 B-fragment, pure register ops
__device__ __forceinline__ short8 ld_bfrag(const float* p) {
    float4 a = *(const float4*)p;
    float4 c = *(const float4*)(p + 4);
    uint4 u;
    u.x = pk2(a.x, a.y);
    u.y = pk2(a.z, a.w);
    u.z = pk2(c.x, c.y);
    u.w = pk2(c.z, c.w);
    return __builtin_bit_cast(short8, u);
}

// async DMA one 32x200 f32 tile -> LDS (25 x 1024B wave-instructions, strided by wave)
// LDS dest: wave-uniform base + lane*16 (HW); global src: per-lane base + lane*16.
__device__ __forceinline__ void dma_tile(const float* __restrict__ g, float* l,
                                         int w, int lane) {
    #pragma unroll
    for (int j = 0; j < 7; j++) {
        int i = w + j * 4;            // wave-uniform
        if (i < 25) {
            __builtin_amdgcn_global_load_lds(
                (const __attribute__((address_space(1))) void*)(g + i * 256 + lane * 4),
                (__attribute__((address_space(3))) void*)(l + i * 256),
                16, 0, 0);
        }
    }
}

// ---------------- prep_all ----------------
// blocks 0..255    : Uab row (bf16, zero-padded [256][224])
// blocks 256..455  : W_ihT[k][j] = W_ih[j][1+k]
// blocks 456..655  : W_hhT[k][j] = W_hh[j][k]
// block  656       : wx[j] = W_ih[j][0]
// blocks 657..784  : qb[b][h] = h0[b] @ Wa.T + ba + bua   (float4 dot)
// blocks 785..984  : W1T[k][j] = W1[j][k]   (k<200, j<100)
// blocks 985..1084 : W2T[k][j] = W2[j][k]   (k<100, j<50)
__global__ __launch_bounds__(256) void prep_all(const float* __restrict__ Ua,
                                                const float* __restrict__ Wa,
                                                const float* __restrict__ ba,
                                                const float* __restrict__ bua,
                                                const float* __restrict__ h0,
                                                const float* __restrict__ W_ih,
                                                const float* __restrict__ W_hh,
                                                const float* __restrict__ W1,
                                                const float* __restrict__ W2,
                                                unsigned short* __restrict__ Uab,
                                                float* __restrict__ WihT,
                                                float* __restrict__ WhhT,
                                                float* __restrict__ wx,
                                                float* __restrict__ qb,
                                                float* __restrict__ W1T,
                                                float* __restrict__ W2T) {
    __shared__ __align__(16) float qs[H];
    int bx = blockIdx.x, tid = threadIdx.x;
    if (bx < 256) {
        if (tid < KP) {
            float v = (bx < H && tid < H) ? Ua[bx * H + tid] : 0.f;
            Uab[bx * KP + tid] = f2bf(v);
        }
    } else if (bx < 456) {
        int k = bx - 256;
        for (int j = tid; j < G4; j += 256) WihT[k * G4 + j] = W_ih[(size_t)j * (H + 1) + 1 + k];
    } else if (bx < 656) {
        int k = bx - 456;
        for (int j = tid; j < G4; j += 256) WhhT[k * G4 + j] = W_hh[(size_t)j * H + k];
    } else if (bx == 656) {
        for (int j = tid; j < G4; j += 256) wx[j] = W_ih[(size_t)j * (H + 1)];
    } else if (bx < 785) {
        int b = bx - 657;
        if (tid < H) qs[tid] = h0[b * H + tid];
        __syncthreads();
        if (tid < H) {
            float a = ba[tid] + bua[tid];
            const float4* w  = (const float4*)(Wa + tid * H);
            const float4* qv = (const float4*)qs;
            #pragma unroll 8
            for (int k = 0; k < 50; k++) {
                float4 wv = w[k], q4 = qv[k];
                a = fmaf(wv.x, q4.x, a);
                a = fmaf(wv.y, q4.y, a);
                a = fmaf(wv.z, q4.z, a);
                a = fmaf(wv.w, q4.w, a);
            }
            qb[b * H + tid] = a;
        }
    } else if (bx < 985) {
        int k = bx - 785;
        if (tid < 100) W1T[k * 100 + tid] = W1[tid * H + k];
    } else {
        int k = bx - 985;
        if (tid < 50) W2T[k * 50 + tid] = W2[tid * 100 + k];
    }
}

// ---------------- scores + bounded-softmax + context (DMA-pipelined) ----------------
// Grid: 2048 = (b, 1/16 of T). Each block: 4 tiles of 32 rows, double-buffered f32
// LDS filled by global_load_lds (zero VGPR staging -> no spill engine). Per tile:
// scores (af transient from L2-hot Uab, B-frags f32 ds_read + pk2) -> softmax ->
// issue next DMA -> ctx pass (covers DMA latency) -> syncthreads drain.

template<int NM>
__device__ __forceinline__ void mig_scores(const unsigned short* __restrict__ Uab,
                                           const float* bufc,
                                           const float* s_va, const float* s_qb,
                                           int m0, int r, int q, float p[2]) {
    short8 af[NM][7];
    #pragma unroll
    for (int m = 0; m < NM; m++)
        #pragma unroll
        for (int ks = 0; ks < 7; ks++)
            af[m][ks] = *(const short8*)(Uab + ((m0 + m) * 16 + r) * KP + ks * 32 + q * 8);
    #pragma unroll
    for (int nt = 0; nt < 2; nt++) {
        const float* rowp = bufc + (nt * 16 + r) * H;
        floatx4 C[NM];
        #pragma unroll
        for (int m = 0; m < NM; m++) C[m] = (floatx4){0.f, 0.f, 0.f, 0.f};
        #pragma unroll
        for (int ks = 0; ks < 7; ks++) {
            short8 bf;
            if (ks < 6) {
                bf = ld_bfrag(rowp + ks * 32 + q * 8);
            } else if (q == 0) {
                bf = ld_bfrag(rowp + 192);
            } else {
                short8 z = {0, 0, 0, 0, 0, 0, 0, 0};
                bf = z;
            }
            #pragma unroll
            for (int m = 0; m < NM; m++)
                C[m] = __builtin_amdgcn_mfma_f32_16x16x32_bf16(af[m][ks], bf, C[m], 0, 0, 0);
        }
        float pp = 0.f;
        #pragma unroll
        for (int m = 0; m < NM; m++)
            #pragma unroll
            for (int g = 0; g < 4; g++) {
                int h = (m0 + m) * 16 + q * 4 + g;
                pp += s_va[h] * ftanh(s_qb[h] + C[m][g]);
            }
        p[nt] += pp;
    }
}

__global__ __launch_bounds__(256, 3) void scores_ctx(const float* __restrict__ enc,
                                                     const unsigned short* __restrict__ Uab,
                                                     const float* __restrict__ qb,
                                                     const float* __restrict__ Va,
                                                     const float* __restrict__ bva,
                                                     float* __restrict__ ctx_raw,
                                                     float* __restrict__ lsum) {
    __shared__ __align__(16) float ebuf[2][TFLOAT];   // 2 x 25600 B
    __shared__ float part[4][ROWS];
    __shared__ float s_qb[256];
    __shared__ float s_va[256];
    __shared__ float wlds[ROWS];

    int bx  = blockIdx.x;
    int b   = bx >> 4;
    int t0  = (bx & 15) * (ROWS * NTILE);
    int tid = threadIdx.x, w = tid >> 6, lane = tid & 63, r = lane & 15, q = lane >> 4;

    const float* gchunk = enc + (size_t)(b * T + t0) * H;

    dma_tile(gchunk, ebuf[0], w, lane);   // tile 0 in flight

    s_qb[tid] = (tid < H) ? qb[b * H + tid] : 0.f;
    s_va[tid] = (tid < H) ? Va[tid] : 0.f;
    float bv = bva[0];
    __syncthreads();   // s_* ready; tile-0 DMA drained (covered by the staging above)

    float bound = 0.f;   // sum|Va| + |bva| (wave 0)
    if (tid < 64) {
        float a = fabsf(s_va[tid]) + fabsf(s_va[tid + 64]) +
                  fabsf(s_va[tid + 128]) + fabsf(s_va[tid + 192]);
        #pragma unroll
        for (int d = 1; d < 64; d <<= 1) a += __shfl_xor(a, d);
        bound = a + fabsf(bv);
    }

    float ca0 = 0.f, ca1 = 0.f, ca2 = 0.f, ca3 = 0.f;   // ctx accum across tiles
    float lacc = 0.f;                                    // lsum accum (wave0, lane<32)

    for (int tile = 0; tile < NTILE; tile++) {
        const float* bufc = ebuf[tile & 1];

        // --- scores: 13 m-tiles, af transient from L2-hot Uab, B from LDS f32 ---
        float p[2] = {0.f, 0.f};
        if (w == 0) {
            mig_scores<2>(Uab, bufc, s_va, s_qb, 0, r, q, p);
            mig_scores<2>(Uab, bufc, s_va, s_qb, 2, r, q, p);
        } else {
            int mbase = 1 + 3 * w;
            mig_scores<2>(Uab, bufc, s_va, s_qb, mbase, r, q, p);
            mig_scores<1>(Uab, bufc, s_va, s_qb, mbase + 2, r, q, p);
        }
        #pragma unroll
        for (int nt = 0; nt < 2; nt++) {
            float pp = p[nt];
            pp += __shfl_xor(pp, 16);
            pp += __shfl_xor(pp, 32);
            if (q == 0) part[w][nt * 16 + r] = pp;
        }
        __syncthreads();   // (no DMA outstanding here)

        if (tid < ROWS) {   // wave 0: score -> bounded-softmax weight
            float s  = part[0][tid] + part[1][tid] + part[2][tid] + part[3][tid] + bv;
            float we = __builtin_amdgcn_exp2f((s - bound) * 1.4426950408889634f);
            wlds[tid] = we;
            lacc += we;
        }
        __syncthreads();   // wlds visible (no DMA outstanding)

        // --- issue next tile's DMA; ctx pass below covers its latency ---
        if (tile < NTILE - 1)
            dma_tile(gchunk + (tile + 1) * TFLOAT, ebuf[(tile & 1) ^ 1], w, lane);

        if (tid < H) {   // ctx[h] += sum_t w[t]*enc[t,h], f32 from LDS (bank-clean)
            #pragma unroll 4
            for (int t = 0; t < ROWS; t += 4) {
                ca0 = fmaf(wlds[t],     bufc[(t    ) * H + tid], ca0);
                ca1 = fmaf(wlds[t + 1], bufc[(t + 1) * H + tid], ca1);
                ca2 = fmaf(wlds[t + 2], bufc[(t + 2) * H + tid], ca2);
                ca3 = fmaf(wlds[t + 3], bufc[(t + 3) * H + tid], ca3);
            }
        }
        __syncthreads();   // drains next-tile DMA (covered by ctx) + read-write fence
    }

    if (tid < H) atomicAdd(&ctx_raw[b * H + tid], (ca0 + ca1) + (ca2 + ca3));
    if (tid < ROWS) {   // wave0: reduce lacc over 32 lanes, one atomic
        #pragma unroll
        for (int d = 1; d < 32; d <<= 1) lacc += __shfl_xor(lacc, d);
        if (tid == 0) atomicAdd(&lsum[b], lacc);
    }
}

// ---------------- decoder (fused gc prologue + 5 steps), 512 threads ----------------
__global__ __launch_bounds__(512) void decoder2(const float* __restrict__ x,
                                                const float* __restrict__ c0,
                                                const float* __restrict__ ctx_raw,
                                                const float* __restrict__ lsum,
                                                const float* __restrict__ h0,
                                                const float* __restrict__ WihT,
                                                const float* __restrict__ WhhT,
                                                const float* __restrict__ b_ih,
                                                const float* __restrict__ b_hh,
                                                const float* __restrict__ wx,
                                                const float* __restrict__ W1T,
                                                const float* __restrict__ b1,
                                                const float* __restrict__ W2T,
                                                const float* __restrict__ b2,
                                                const float* __restrict__ W3,
                                                const float* __restrict__ b3,
                                                float* __restrict__ out) {
    __shared__ float s_gc[G4];
    __shared__ float s_wx[G4];
    __shared__ float s_ctx[H];
    __shared__ float s_q[H];
    __shared__ float s_out[H];
    __shared__ float s_o1[100];
    __shared__ float s_o2[50];
    __shared__ float s_w3[64];
    __shared__ float s_x;
    int b = blockIdx.x, tid = threadIdx.x;

    if (tid < H) {
        float invl = 1.f / lsum[b];
        s_ctx[tid] = ctx_raw[b * H + tid] * invl;
        s_q[tid]   = h0[b * H + tid];
    }
    s_wx[tid] = wx[tid];
    if (tid < G4 - 512) s_wx[512 + tid] = wx[512 + tid];
    if (tid < 64) s_w3[tid] = (tid < 50) ? W3[tid] : 0.f;
    if (tid == 0) s_x = x[b];
    float b3v = b3[0];
    __syncthreads();

    // gc[j] = b_ih+b_hh + ctx.Wih[:,1:] + q.Whh   (two j per thread)
    {
        int j0 = tid;
        int j1 = 512 + ((tid < 288) ? tid : 287);
        float a0 = b_ih[j0] + b_hh[j0];
        float a1 = b_ih[j1] + b_hh[j1];
        #pragma unroll 4
        for (int k = 0; k < H; k++) {
            float cv = s_ctx[k], qv = s_q[k];
            a0 = fmaf(cv, WihT[k * G4 + j0], a0);
            a0 = fmaf(qv, WhhT[k * G4 + j0], a0);
            a1 = fmaf(cv, WihT[k * G4 + j1], a1);
            a1 = fmaf(qv, WhhT[k * G4 + j1], a1);
        }
        s_gc[j0] = a0;
        if (tid < 288) s_gc[512 + tid] = a1;
    }
    float cprev = (tid < H) ? c0[b * H + tid] : 0.f;
    __syncthreads();

    for (int s = 0; s < 5; s++) {
        float xv = s_x;
        if (tid < H) {
            float ig = s_gc[tid]         + xv * s_wx[tid];
            float fg = s_gc[H + tid]     + xv * s_wx[H + tid];
            float gg = s_gc[2 * H + tid] + xv * s_wx[2 * H + tid];
            float og = s_gc[3 * H + tid] + xv * s_wx[3 * H + tid];
            float c  = sigm(fg) * cprev + sigm(ig) * tanhf(gg);
            float hn = sigm(og) * tanhf(c);
            s_out[tid] = fmaxf(hn, 0.f);
        }
        __syncthreads();
        if (tid < 400) {   // W1: 4 lanes per output, k split 4x50
            int j = tid >> 2, q4 = tid & 3;
            float a = 0.f;
            const float* wp = W1T + (q4 * 50) * 100 + j;
            const float* op = s_out + q4 * 50;
            #pragma unroll 10
            for (int k = 0; k < 50; k++) a = fmaf(wp[k * 100], op[k], a);
            a += __shfl_xor(a, 1);
            a += __shfl_xor(a, 2);
            if (q4 == 0) s_o1[j] = fmaxf(a + b1[j], 0.f);
        }
        __syncthreads();
        if (tid < 200) {   // W2: 4 lanes per output, k split 4x25
            int j = tid >> 2, q4 = tid & 3;
            float a = 0.f;
            const float* wp = W2T + (q4 * 25) * 50 + j;
            const float* op = s_o1 + q4 * 25;
            #pragma unroll 5
            for (int k = 0; k < 25; k++) a = fmaf(wp[k * 50], op[k], a);
            a += __shfl_xor(a, 1);
            a += __shfl_xor(a, 2);
            if (q4 == 0) s_o2[j] = fmaxf(a + b2[j], 0.f);
        }
        __syncthreads();
        if (tid < 64) {   // W3: wave reduce
            float a = (tid < 50) ? s_w3[tid] * s_o2[tid] : 0.f;
            #pragma unroll
            for (int d = 1; d < 64; d <<= 1) a += __shfl_xor(a, d);
            if (tid == 0) {
                float y = a + b3v;
                out[b * 5 + s] = y;
                s_x = y;
            }
        }
        __syncthreads();
    }
}

// ---------------- launch ----------------
extern "C" void kernel_launch(void* const* d_in, const int* in_sizes, int n_in,
                              void* d_out, int out_size, void* d_ws, size_t ws_size,
                              hipStream_t stream) {
    (void)in_sizes; (void)n_in; (void)out_size; (void)ws_size;
    const float* x    = (const float*)d_in[0];
    const float* h0   = (const float*)d_in[1];
    const float* c0   = (const float*)d_in[2];
    const float* enc  = (const float*)d_in[3];
    const float* Wa   = (const float*)d_in[4];
    const float* ba   = (const float*)d_in[5];
    const float* Ua   = (const float*)d_in[6];
    const float* bua  = (const float*)d_in[7];
    const float* Va   = (const float*)d_in[8];
    const float* bva  = (const float*)d_in[9];
    const float* W_ih = (const float*)d_in[10];
    const float* W_hh = (const float*)d_in[11];
    const float* b_ih = (const float*)d_in[12];
    const float* b_hh = (const float*)d_in[13];
    const float* W1   = (const float*)d_in[14];
    const float* b1   = (const float*)d_in[15];
    const float* W2   = (const float*)d_in[16];
    const float* b2   = (const float*)d_in[17];
    const float* W3   = (const float*)d_in[18];
    const float* b3   = (const float*)d_in[19];
    float* out = (float*)d_out;

    char* ws = (char*)d_ws;
    unsigned short* Uab = (unsigned short*)(ws);   // 114688
    float* WihT    = (float*)(ws + 114688);        // 640000
    float* WhhT    = (float*)(ws + 754688);        // 640000
    float* wx      = (float*)(ws + 1394688);       // 3200
    float* qb      = (float*)(ws + 1397888);       // 102400
    float* W1T     = (float*)(ws + 1500288);       // 80000
    float* W2T     = (float*)(ws + 1580288);       // 20000
    float* ctx_raw = (float*)(ws + 1600288);       // 102400
    float* lsum    = (float*)(ws + 1702688);       // 512

    hipMemsetAsync(ws + 1600288, 0, 102912, stream);   // ctx_raw + lsum
    prep_all<<<dim3(1085), 256, 0, stream>>>(Ua, Wa, ba, bua, h0, W_ih, W_hh, W1, W2,
                                             Uab, WihT, WhhT, wx, qb, W1T, W2T);
    scores_ctx<<<dim3(2048), 256, 0, stream>>>(enc, Uab, qb, Va, bva, ctx_raw, lsum);
    decoder2<<<dim3(B), 512, 0, stream>>>(x, c0, ctx_raw, lsum, h0, WihT, WhhT,
                                          b_ih, b_hh, wx, W1T, b1, W2T, b2, W3, b3, out);
}

// Round 5
// 183.064 us; speedup vs baseline: 1.9655x; 1.0858x over previous
//
#include <hip/hip_runtime.h>
#include <math.h>

#define B 128
#define T 2048
#define H 200
#define G4 800   // 4*H
#define KP 224   // Uab row stride (bf16), K padded to multiple of 32
#define ROWS 16  // t-rows per tile
#define NTILE 8  // tiles per block (chunk = 128 rows)
#define TBYTES (ROWS * H * 4)   // 12800 B payload per tile
#define BUFF 3328               // floats per LDS buffer (13 x 1024 B, incl. pad)

typedef short short8 __attribute__((ext_vector_type(8)));
typedef float floatx4 __attribute__((ext_vector_type(4)));

__device__ __forceinline__ unsigned short f2bf(float x) {
    unsigned u = __float_as_uint(x);
    return (unsigned short)((u + 0x7fffu + ((u >> 16) & 1u)) >> 16);
}
// pack two floats -> two bf16 (round-nearest-away) in 3 VALU ops
__device__ __forceinline__ unsigned pk2(float a, float b) {
    return __builtin_amdgcn_perm(__float_as_uint(b) + 0x8000u,
                                 __float_as_uint(a) + 0x8000u, 0x07060302u);
}
// tanh(x) = 1 - 2/(exp(2x)+1), hw exp2 + rcp (~1e-6 rel err)
__device__ __forceinline__ float ftanh(float x) {
    float e = __builtin_amdgcn_exp2f(x * 2.885390081777927f);
    float r = __builtin_amdgcn_rcpf(e + 1.f);
    return fmaf(-2.f, r, 1.f);
}
__device__ __forceinline__ float sigm(float x) { return 1.f / (1.f + expf(-x)); }

// 8 consecutive f32 (LDS) -> bf16 short8 B-fragment, pure register ops
__device__ __forceinline__ short8 ld_bfrag(const float* p) {
    float4 a = *(const float4*)p;
    float4 c = *(const float4*)(p + 4);
    uint4 u;
    u.x = pk2(a.x, a.y);
    u.y = pk2(a.z, a.w);
    u.z = pk2(c.x, c.y);
    u.w = pk2(c.z, c.w);
    return __builtin_bit_cast(short8, u);
}

// async DMA one 16x200 f32 tile -> LDS. 13 wave-chunks of 1024 B (12800 B payload
// + 512 B pad). Chunk 12's pad lanes (off >= 12800) clamp their SOURCE to the tile
// start (per-lane source is legal) so we never read OOB; the pad LDS region is
// never read. LDS dest is wave-uniform base; HW adds lane*16.
__device__ __forceinline__ void dma_tile16(const float* __restrict__ g, float* l,
                                           int w, int lane) {
    #pragma unroll
    for (int j = 0; j < 4; j++) {
        int i = w + j * 4;              // wave-uniform chunk id
        if (i < 13) {
            int off  = i * 1024 + lane * 16;
            int soff = (off < TBYTES) ? off : 0;
            __builtin_amdgcn_global_load_lds(
                (const __attribute__((address_space(1))) void*)((const char*)g + soff),
                (__attribute__((address_space(3))) void*)((char*)l + i * 1024),
                16, 0, 0);
        }
    }
}

// ---------------- prep_all ----------------
// blocks 0..255    : Uab row (bf16, zero-padded [256][224])
// blocks 256..455  : W_ihT[k][j] = W_ih[j][1+k]
// blocks 456..655  : W_hhT[k][j] = W_hh[j][k]
// block  656       : wx[j] = W_ih[j][0]
// blocks 657..784  : qb[b][h] = h0[b] @ Wa.T + ba + bua   (float4 dot)
// blocks 785..984  : W1T[k][j] = W1[j][k]   (k<200, j<100)
// blocks 985..1084 : W2T[k][j] = W2[j][k]   (k<100, j<50)
__global__ __launch_bounds__(256) void prep_all(const float* __restrict__ Ua,
                                                const float* __restrict__ Wa,
                                                const float* __restrict__ ba,
                                                const float* __restrict__ bua,
                                                const float* __restrict__ h0,
                                                const float* __restrict__ W_ih,
                                                const float* __restrict__ W_hh,
                                                const float* __restrict__ W1,
                                                const float* __restrict__ W2,
                                                unsigned short* __restrict__ Uab,
                                                float* __restrict__ WihT,
                                                float* __restrict__ WhhT,
                                                float* __restrict__ wx,
                                                float* __restrict__ qb,
                                                float* __restrict__ W1T,
                                                float* __restrict__ W2T) {
    __shared__ __align__(16) float qs[H];
    int bx = blockIdx.x, tid = threadIdx.x;
    if (bx < 256) {
        if (tid < KP) {
            float v = (bx < H && tid < H) ? Ua[bx * H + tid] : 0.f;
            Uab[bx * KP + tid] = f2bf(v);
        }
    } else if (bx < 456) {
        int k = bx - 256;
        for (int j = tid; j < G4; j += 256) WihT[k * G4 + j] = W_ih[(size_t)j * (H + 1) + 1 + k];
    } else if (bx < 656) {
        int k = bx - 456;
        for (int j = tid; j < G4; j += 256) WhhT[k * G4 + j] = W_hh[(size_t)j * H + k];
    } else if (bx == 656) {
        for (int j = tid; j < G4; j += 256) wx[j] = W_ih[(size_t)j * (H + 1)];
    } else if (bx < 785) {
        int b = bx - 657;
        if (tid < H) qs[tid] = h0[b * H + tid];
        __syncthreads();
        if (tid < H) {
            float a = ba[tid] + bua[tid];
            const float4* w  = (const float4*)(Wa + tid * H);
            const float4* qv = (const float4*)qs;
            #pragma unroll 8
            for (int k = 0; k < 50; k++) {
                float4 wv = w[k], q4 = qv[k];
                a = fmaf(wv.x, q4.x, a);
                a = fmaf(wv.y, q4.y, a);
                a = fmaf(wv.z, q4.z, a);
                a = fmaf(wv.w, q4.w, a);
            }
            qb[b * H + tid] = a;
        }
    } else if (bx < 985) {
        int k = bx - 785;
        if (tid < 100) W1T[k * 100 + tid] = W1[tid * H + k];
    } else {
        int k = bx - 985;
        if (tid < 50) W2T[k * 50 + tid] = W2[tid * 100 + k];
    }
}

// ---------------- scores + bounded-softmax + context ----------------
// Grid: 2048 = (b, 1/16 of T). 8 tiles x 16 rows, double-buffered f32 LDS via
// global_load_lds (zero VGPR staging). Iteration t: top-issue DMA(t+1) (buffer
// safe since its last readers finished before barrier B(t-1)); scores(t) covers
// the DMA latency; barrier A drains; ctx(t) with per-thread redundant softmax
// (16 exp2, LDS-broadcast part reads -> no wave0 serialization, no 3rd barrier);
// barrier B fences buffer reuse. ~29 KB LDS -> 4 blocks/CU (128 KB usable model).

template<int NM>
__device__ __forceinline__ float mig1(const unsigned short* __restrict__ Uab,
                                      const float* rowp,
                                      const float* s_va, const float* s_qb,
                                      int m0, int r, int q) {
    short8 af[NM][7];
    #pragma unroll
    for (int m = 0; m < NM; m++)
        #pragma unroll
        for (int ks = 0; ks < 7; ks++)
            af[m][ks] = *(const short8*)(Uab + ((m0 + m) * 16 + r) * KP + ks * 32 + q * 8);
    floatx4 C[NM];
    #pragma unroll
    for (int m = 0; m < NM; m++) C[m] = (floatx4){0.f, 0.f, 0.f, 0.f};
    #pragma unroll
    for (int ks = 0; ks < 7; ks++) {
        short8 bf;
        if (ks < 6) {
            bf = ld_bfrag(rowp + ks * 32 + q * 8);
        } else if (q == 0) {
            bf = ld_bfrag(rowp + 192);
        } else {
            short8 z = {0, 0, 0, 0, 0, 0, 0, 0};
            bf = z;
        }
        #pragma unroll
        for (int m = 0; m < NM; m++)
            C[m] = __builtin_amdgcn_mfma_f32_16x16x32_bf16(af[m][ks], bf, C[m], 0, 0, 0);
    }
    float pp = 0.f;
    #pragma unroll
    for (int m = 0; m < NM; m++)
        #pragma unroll
        for (int g = 0; g < 4; g++) {
            int h = (m0 + m) * 16 + q * 4 + g;
            pp += s_va[h] * ftanh(s_qb[h] + C[m][g]);
        }
    return pp;
}

__global__ __launch_bounds__(256, 4) void scores_ctx(const float* __restrict__ enc,
                                                     const unsigned short* __restrict__ Uab,
                                                     const float* __restrict__ qb,
                                                     const float* __restrict__ Va,
                                                     const float* __restrict__ bva,
                                                     float* __restrict__ ctx_raw,
                                                     float* __restrict__ lsum) {
    __shared__ __align__(16) float ebuf[2][BUFF];   // 2 x 13312 B
    __shared__ float part[4][ROWS];
    __shared__ float s_qb[256];
    __shared__ float s_va[256];

    int bx  = blockIdx.x;
    int b   = bx >> 4;
    int t0  = (bx & 15) * (ROWS * NTILE);
    int tid = threadIdx.x, w = tid >> 6, lane = tid & 63, r = lane & 15, q = lane >> 4;

    const float* gchunk = enc + (size_t)(b * T + t0) * H;

    dma_tile16(gchunk, ebuf[0], w, lane);   // tile 0 in flight

    s_qb[tid] = (tid < H) ? qb[b * H + tid] : 0.f;
    s_va[tid] = (tid < H) ? Va[tid] : 0.f;
    float bv = bva[0];
    __syncthreads();   // s_* ready; tile-0 DMA drained

    // score bound = sum|Va| + |bva|, computed redundantly per wave (all threads get it)
    float bound;
    {
        float a = fabsf(s_va[lane]) + fabsf(s_va[lane + 64]) +
                  fabsf(s_va[lane + 128]) + fabsf(s_va[lane + 192]);
        #pragma unroll
        for (int d = 1; d < 64; d <<= 1) a += __shfl_xor(a, d);
        bound = a + fabsf(bv);
    }
    const float l2e = 1.4426950408889634f;

    float ca = 0.f;      // ctx accumulator: one h (=tid) per thread
    float lacc = 0.f;    // weight-sum accumulator (identical across threads; tid0 commits)

    for (int tile = 0; tile < NTILE; tile++) {
        const float* bufc = ebuf[tile & 1];

        // A: top-issue next tile's DMA; covered by the scores phase below
        if (tile < NTILE - 1)
            dma_tile16(gchunk + (size_t)(tile + 1) * ROWS * H, ebuf[(tile & 1) ^ 1], w, lane);

        // B: scores for 16 rows; 13 m-tiles split {4,3,3,3} across waves
        const float* rowp = bufc + r * H;
        float pp;
        if (w == 0) {
            pp = mig1<2>(Uab, rowp, s_va, s_qb, 0, r, q)
               + mig1<2>(Uab, rowp, s_va, s_qb, 2, r, q);
        } else {
            int mb = 1 + 3 * w;
            pp = mig1<2>(Uab, rowp, s_va, s_qb, mb, r, q)
               + mig1<1>(Uab, rowp, s_va, s_qb, mb + 2, r, q);
        }
        pp += __shfl_xor(pp, 16);
        pp += __shfl_xor(pp, 32);
        if (q == 0) part[w][r] = pp;
        __syncthreads();   // A: part visible; drains DMA(t+1) (covered by scores)

        // C: redundant softmax + ctx accumulate (no wave0 serialization)
        if (tid < H) {
            #pragma unroll
            for (int tt = 0; tt < ROWS; tt++) {
                float s  = part[0][tt] + part[1][tt] + part[2][tt] + part[3][tt] + bv;
                float we = __builtin_amdgcn_exp2f((s - bound) * l2e);
                lacc += we;
                ca = fmaf(we, bufc[tt * H + tid], ca);
            }
        }
        __syncthreads();   // B: buffer-reuse fence (nothing to drain)
    }

    if (tid < H) atomicAdd(&ctx_raw[b * H + tid], ca);
    if (tid == 0) atomicAdd(&lsum[b], lacc);
}

// ---------------- decoder (fused gc prologue + 5 steps), 512 threads ----------------
__global__ __launch_bounds__(512) void decoder2(const float* __restrict__ x,
                                                const float* __restrict__ c0,
                                                const float* __restrict__ ctx_raw,
                                                const float* __restrict__ lsum,
                                                const float* __restrict__ h0,
                                                const float* __restrict__ WihT,
                                                const float* __restrict__ WhhT,
                                                const float* __restrict__ b_ih,
                                                const float* __restrict__ b_hh,
                                                const float* __restrict__ wx,
                                                const float* __restrict__ W1T,
                                                const float* __restrict__ b1,
                                                const float* __restrict__ W2T,
                                                const float* __restrict__ b2,
                                                const float* __restrict__ W3,
                                                const float* __restrict__ b3,
                                                float* __restrict__ out) {
    __shared__ float s_gc[G4];
    __shared__ float s_wx[G4];
    __shared__ float s_ctx[H];
    __shared__ float s_q[H];
    __shared__ float s_out[H];
    __shared__ float s_o1[100];
    __shared__ float s_o2[50];
    __shared__ float s_w3[64];
    __shared__ float s_x;
    int b = blockIdx.x, tid = threadIdx.x;

    if (tid < H) {
        float invl = 1.f / lsum[b];
        s_ctx[tid] = ctx_raw[b * H + tid] * invl;
        s_q[tid]   = h0[b * H + tid];
    }
    s_wx[tid] = wx[tid];
    if (tid < G4 - 512) s_wx[512 + tid] = wx[512 + tid];
    if (tid < 64) s_w3[tid] = (tid < 50) ? W3[tid] : 0.f;
    if (tid == 0) s_x = x[b];
    float b3v = b3[0];
    __syncthreads();

    // gc[j] = b_ih+b_hh + ctx.Wih[:,1:] + q.Whh   (two j per thread)
    {
        int j0 = tid;
        int j1 = 512 + ((tid < 288) ? tid : 287);
        float a0 = b_ih[j0] + b_hh[j0];
        float a1 = b_ih[j1] + b_hh[j1];
        #pragma unroll 4
        for (int k = 0; k < H; k++) {
            float cv = s_ctx[k], qv = s_q[k];
            a0 = fmaf(cv, WihT[k * G4 + j0], a0);
            a0 = fmaf(qv, WhhT[k * G4 + j0], a0);
            a1 = fmaf(cv, WihT[k * G4 + j1], a1);
            a1 = fmaf(qv, WhhT[k * G4 + j1], a1);
        }
        s_gc[j0] = a0;
        if (tid < 288) s_gc[512 + tid] = a1;
    }
    float cprev = (tid < H) ? c0[b * H + tid] : 0.f;
    __syncthreads();

    for (int s = 0; s < 5; s++) {
        float xv = s_x;
        if (tid < H) {
            float ig = s_gc[tid]         + xv * s_wx[tid];
            float fg = s_gc[H + tid]     + xv * s_wx[H + tid];
            float gg = s_gc[2 * H + tid] + xv * s_wx[2 * H + tid];
            float og = s_gc[3 * H + tid] + xv * s_wx[3 * H + tid];
            float c  = sigm(fg) * cprev + sigm(ig) * tanhf(gg);
            float hn = sigm(og) * tanhf(c);
            s_out[tid] = fmaxf(hn, 0.f);
        }
        __syncthreads();
        if (tid < 400) {   // W1: 4 lanes per output, k split 4x50
            int j = tid >> 2, q4 = tid & 3;
            float a = 0.f;
            const float* wp = W1T + (q4 * 50) * 100 + j;
            const float* op = s_out + q4 * 50;
            #pragma unroll 10
            for (int k = 0; k < 50; k++) a = fmaf(wp[k * 100], op[k], a);
            a += __shfl_xor(a, 1);
            a += __shfl_xor(a, 2);
            if (q4 == 0) s_o1[j] = fmaxf(a + b1[j], 0.f);
        }
        __syncthreads();
        if (tid < 200) {   // W2: 4 lanes per output, k split 4x25
            int j = tid >> 2, q4 = tid & 3;
            float a = 0.f;
            const float* wp = W2T + (q4 * 25) * 50 + j;
            const float* op = s_o1 + q4 * 25;
            #pragma unroll 5
            for (int k = 0; k < 25; k++) a = fmaf(wp[k * 50], op[k], a);
            a += __shfl_xor(a, 1);
            a += __shfl_xor(a, 2);
            if (q4 == 0) s_o2[j] = fmaxf(a + b2[j], 0.f);
        }
        __syncthreads();
        if (tid < 64) {   // W3: wave reduce
            float a = (tid < 50) ? s_w3[tid] * s_o2[tid] : 0.f;
            #pragma unroll
            for (int d = 1; d < 64; d <<= 1) a += __shfl_xor(a, d);
            if (tid == 0) {
                float y = a + b3v;
                out[b * 5 + s] = y;
                s_x = y;
            }
        }
        __syncthreads();
    }
}

// ---------------- launch ----------------
extern "C" void kernel_launch(void* const* d_in, const int* in_sizes, int n_in,
                              void* d_out, int out_size, void* d_ws, size_t ws_size,
                              hipStream_t stream) {
    (void)in_sizes; (void)n_in; (void)out_size; (void)ws_size;
    const float* x    = (const float*)d_in[0];
    const float* h0   = (const float*)d_in[1];
    const float* c0   = (const float*)d_in[2];
    const float* enc  = (const float*)d_in[3];
    const float* Wa   = (const float*)d_in[4];
    const float* ba   = (const float*)d_in[5];
    const float* Ua   = (const float*)d_in[6];
    const float* bua  = (const float*)d_in[7];
    const float* Va   = (const float*)d_in[8];
    const float* bva  = (const float*)d_in[9];
    const float* W_ih = (const float*)d_in[10];
    const float* W_hh = (const float*)d_in[11];
    const float* b_ih = (const float*)d_in[12];
    const float* b_hh = (const float*)d_in[13];
    const float* W1   = (const float*)d_in[14];
    const float* b1   = (const float*)d_in[15];
    const float* W2   = (const float*)d_in[16];
    const float* b2   = (const float*)d_in[17];
    const float* W3   = (const float*)d_in[18];
    const float* b3   = (const float*)d_in[19];
    float* out = (float*)d_out;

    char* ws = (char*)d_ws;
    unsigned short* Uab = (unsigned short*)(ws);   // 114688
    float* WihT    = (float*)(ws + 114688);        // 640000
    float* WhhT    = (float*)(ws + 754688);        // 640000
    float* wx      = (float*)(ws + 1394688);       // 3200
    float* qb      = (float*)(ws + 1397888);       // 102400
    float* W1T     = (float*)(ws + 1500288);       // 80000
    float* W2T     = (float*)(ws + 1580288);       // 20000
    float* ctx_raw = (float*)(ws + 1600288);       // 102400
    float* lsum    = (float*)(ws + 1702688);       // 512

    hipMemsetAsync(ws + 1600288, 0, 102912, stream);   // ctx_raw + lsum
    prep_all<<<dim3(1085), 256, 0, stream>>>(Ua, Wa, ba, bua, h0, W_ih, W_hh, W1, W2,
                                             Uab, WihT, WhhT, wx, qb, W1T, W2T);
    scores_ctx<<<dim3(2048), 256, 0, stream>>>(enc, Uab, qb, Va, bva, ctx_raw, lsum);
    decoder2<<<dim3(B), 512, 0, stream>>>(x, c0, ctx_raw, lsum, h0, WihT, WhhT,
                                          b_ih, b_hh, wx, W1T, b1, W2T, b2, W3, b3, out);
}

// Round 7
// 174.531 us; speedup vs baseline: 2.0616x; 1.0489x over previous
//
#include <hip/hip_runtime.h>
#include <math.h>

#define B 128
#define T 2048
#define H 200
#define G4 800    // 4*H
#define KP 224    // Uab row stride (bf16)
#define ESTR 208  // elds row stride (bf16): 200 data + 8 pad (zeroed)
#define ROWS 32   // t-rows per block

typedef short short8 __attribute__((ext_vector_type(8)));
typedef float floatx4 __attribute__((ext_vector_type(4)));

__device__ __forceinline__ unsigned short f2bf(float x) {
    unsigned u = __float_as_uint(x);
    return (unsigned short)((u + 0x7fffu + ((u >> 16) & 1u)) >> 16);
}
__device__ __forceinline__ float bf2f(unsigned short s) {
    return __uint_as_float(((unsigned)s) << 16);
}
// pack two floats -> two bf16 (round-nearest-away) in 3 VALU ops
__device__ __forceinline__ unsigned pk2(float a, float b) {
    return __builtin_amdgcn_perm(__float_as_uint(b) + 0x8000u,
                                 __float_as_uint(a) + 0x8000u, 0x07060302u);
}
// tanh(x) = 1 - 2/(exp(2x)+1), hw exp2 + rcp (~1e-6 rel err)
__device__ __forceinline__ float ftanh(float x) {
    float e = __builtin_amdgcn_exp2f(x * 2.885390081777927f);
    float r = __builtin_amdgcn_rcpf(e + 1.f);
    return fmaf(-2.f, r, 1.f);
}
__device__ __forceinline__ float sigm(float x) { return 1.f / (1.f + expf(-x)); }

// ---------------- prep_all ----------------
// blocks 0..255    : Uab row (bf16, zero-padded [256][224])
// blocks 256..455  : W_ihT[k][j] = W_ih[j][1+k]
// blocks 456..655  : W_hhT[k][j] = W_hh[j][k]
// block  656       : wx[j] = W_ih[j][0]
// blocks 657..784  : qb[b][h] = h0[b] @ Wa.T + ba + bua   (float4 dot)
// blocks 785..984  : W1T[k][j] = W1[j][k]   (k<200, j<100)
// blocks 985..1084 : W2T[k][j] = W2[j][k]   (k<100, j<50)
__global__ __launch_bounds__(256) void prep_all(const float* __restrict__ Ua,
                                                const float* __restrict__ Wa,
                                                const float* __restrict__ ba,
                                                const float* __restrict__ bua,
                                                const float* __restrict__ h0,
                                                const float* __restrict__ W_ih,
                                                const float* __restrict__ W_hh,
                                                const float* __restrict__ W1,
                                                const float* __restrict__ W2,
                                                unsigned short* __restrict__ Uab,
                                                float* __restrict__ WihT,
                                                float* __restrict__ WhhT,
                                                float* __restrict__ wx,
                                                float* __restrict__ qb,
                                                float* __restrict__ W1T,
                                                float* __restrict__ W2T) {
    __shared__ __align__(16) float qs[H];
    int bx = blockIdx.x, tid = threadIdx.x;
    if (bx < 256) {
        if (tid < KP) {
            float v = (bx < H && tid < H) ? Ua[bx * H + tid] : 0.f;
            Uab[bx * KP + tid] = f2bf(v);
        }
    } else if (bx < 456) {
        int k = bx - 256;
        for (int j = tid; j < G4; j += 256) WihT[k * G4 + j] = W_ih[(size_t)j * (H + 1) + 1 + k];
    } else if (bx < 656) {
        int k = bx - 456;
        for (int j = tid; j < G4; j += 256) WhhT[k * G4 + j] = W_hh[(size_t)j * H + k];
    } else if (bx == 656) {
        for (int j = tid; j < G4; j += 256) wx[j] = W_ih[(size_t)j * (H + 1)];
    } else if (bx < 785) {
        int b = bx - 657;
        if (tid < H) qs[tid] = h0[b * H + tid];
        __syncthreads();
        if (tid < H) {
            float a = ba[tid] + bua[tid];
            const float4* w  = (const float4*)(Wa + tid * H);
            const float4* qv = (const float4*)qs;
            #pragma unroll 8
            for (int k = 0; k < 50; k++) {
                float4 wv = w[k], q4 = qv[k];
                a = fmaf(wv.x, q4.x, a);
                a = fmaf(wv.y, q4.y, a);
                a = fmaf(wv.z, q4.z, a);
                a = fmaf(wv.w, q4.w, a);
            }
            qb[b * H + tid] = a;
        }
    } else if (bx < 985) {
        int k = bx - 785;
        if (tid < 100) W1T[k * 100 + tid] = W1[tid * H + k];
    } else {
        int k = bx - 985;
        if (tid < 50) W2T[k * 50 + tid] = W2[tid * 100 + k];
    }
}

// ---------------- scores + bounded-softmax + context (max occupancy) ----------------
// Grid: 8192 = (b, 1/64 of T), 32 rows each. Reg-stage -> bf16 LDS (15.7 KB/block ->
// 8 blocks/CU = 32 waves/CU). k>=200 is annihilated by Uab's zero columns, so the
// ks loop is uniform (7 iters, no branch); elds pad cols + tail are zeroed once to
// avoid NaN*0. 13 m-tiles split {4,3,3,3} across waves. 3 barriers/block.

template<int NM>
__device__ __forceinline__ void migscore(const unsigned short* __restrict__ Uab,
                                         const unsigned short* elds,
                                         const float* s_va, const float* s_qb,
                                         int m0, int r, int q, float p[2]) {
    short8 af[NM][7];
    #pragma unroll
    for (int m = 0; m < NM; m++)
        #pragma unroll
        for (int ks = 0; ks < 7; ks++)
            af[m][ks] = *(const short8*)(Uab + ((m0 + m) * 16 + r) * KP + ks * 32 + q * 8);
    #pragma unroll
    for (int nt = 0; nt < 2; nt++) {
        const unsigned short* rowp = elds + (nt * 16 + r) * ESTR;
        floatx4 C[NM];
        #pragma unroll
        for (int m = 0; m < NM; m++) C[m] = (floatx4){0.f, 0.f, 0.f, 0.f};
        #pragma unroll
        for (int ks = 0; ks < 7; ks++) {
            short8 bf = *(const short8*)(rowp + ks * 32 + q * 8);
            #pragma unroll
            for (int m = 0; m < NM; m++)
                C[m] = __builtin_amdgcn_mfma_f32_16x16x32_bf16(af[m][ks], bf, C[m], 0, 0, 0);
        }
        float pp = 0.f;
        #pragma unroll
        for (int m = 0; m < NM; m++)
            #pragma unroll
            for (int g = 0; g < 4; g++) {
                int h = (m0 + m) * 16 + q * 4 + g;
                pp += s_va[h] * ftanh(s_qb[h] + C[m][g]);
            }
        p[nt] += pp;
    }
}

__global__ __launch_bounds__(256, 8) void scores_ctx(const float* __restrict__ enc,
                                                     const unsigned short* __restrict__ Uab,
                                                     const float* __restrict__ qb,
                                                     const float* __restrict__ Va,
                                                     const float* __restrict__ bva,
                                                     float* __restrict__ ctx_raw,
                                                     float* __restrict__ lsum) {
    __shared__ unsigned short elds[ROWS * ESTR + 32];   // 13376 B (incl 64 B tail pad)
    __shared__ float s_qb[ESTR];                        // 832 B (cols 200..207 zero)
    __shared__ float s_va[ESTR];                        // 832 B
    __shared__ float part[4][ROWS];                     // 512 B
    __shared__ float wlds[ROWS];                        // 128 B

    int bx  = blockIdx.x;
    int b   = bx >> 6;
    int t0  = (bx & 63) * ROWS;
    int tid = threadIdx.x, w = tid >> 6, lane = tid & 63, r = lane & 15, q = lane >> 4;

    // issue stage loads first (coalesced float4; 6400 floats = 1600 float4)
    const float4* gsrc = (const float4*)(enc + (size_t)(b * T + t0) * H);
    float4 rv[7];
    #pragma unroll
    for (int k = 0; k < 6; k++) rv[k] = gsrc[tid + k * 256];
    if (tid < 64) rv[6] = gsrc[tid + 1536];

    if (tid < 200) { s_qb[tid] = qb[b * H + tid]; s_va[tid] = Va[tid]; }
    else if (tid < 208) { s_qb[tid] = 0.f; s_va[tid] = 0.f; }
    float bv = bva[0];

    // zero elds pad: cols 200..207 of each row + 32-short tail (NaN*0 guard)
    if (tid < 128) {
        int row = tid >> 2, pr = tid & 3;
        *(unsigned*)&elds[row * ESTR + 200 + pr * 2] = 0u;
    } else if (tid < 144) {
        *(unsigned*)&elds[ROWS * ESTR + (tid - 128) * 2] = 0u;
    }

    // convert + write bf16 tile (cols 0..199 of each row)
    #pragma unroll
    for (int k = 0; k < 6; k++) {
        int f = tid + k * 256;
        int row = f / 50, c4 = f - row * 50;
        uint2 wv;
        wv.x = pk2(rv[k].x, rv[k].y);
        wv.y = pk2(rv[k].z, rv[k].w);
        *(uint2*)&elds[row * ESTR + c4 * 4] = wv;
    }
    if (tid < 64) {
        int f = tid + 1536;
        int row = f / 50, c4 = f - row * 50;
        uint2 wv;
        wv.x = pk2(rv[6].x, rv[6].y);
        wv.y = pk2(rv[6].z, rv[6].w);
        *(uint2*)&elds[row * ESTR + c4 * 4] = wv;
    }
    __syncthreads();

    // scores: 13 m-tiles {0-3},{4-6},{7-9},{10-12}
    float p[2] = {0.f, 0.f};
    if (w == 0) {
        migscore<2>(Uab, elds, s_va, s_qb, 0, r, q, p);
        migscore<2>(Uab, elds, s_va, s_qb, 2, r, q, p);
    } else {
        int mb = 1 + 3 * w;
        migscore<2>(Uab, elds, s_va, s_qb, mb, r, q, p);
        migscore<1>(Uab, elds, s_va, s_qb, mb + 2, r, q, p);
    }
    #pragma unroll
    for (int nt = 0; nt < 2; nt++) {
        float pp = p[nt];
        pp += __shfl_xor(pp, 16);
        pp += __shfl_xor(pp, 32);
        if (q == 0) part[w][nt * 16 + r] = pp;
    }
    __syncthreads();

    if (w == 0) {   // wave 0: bound + softmax + lsum atomic
        float a = fabsf(s_va[lane]) + fabsf(s_va[lane + 64]) + fabsf(s_va[lane + 128]);
        if (lane < 16) a += fabsf(s_va[lane + 192]);
        #pragma unroll
        for (int d = 1; d < 64; d <<= 1) a += __shfl_xor(a, d);
        float bound = a + fabsf(bv);

        float we = 0.f;
        if (lane < ROWS) {
            float s = part[0][lane] + part[1][lane] + part[2][lane] + part[3][lane] + bv;
            we = __builtin_amdgcn_exp2f((s - bound) * 1.4426950408889634f);
            wlds[lane] = we;
        }
        #pragma unroll
        for (int d = 1; d < 64; d <<= 1) we += __shfl_xor(we, d);
        if (lane == 0) atomicAdd(&lsum[b], we);
    }
    __syncthreads();

    if (tid < H) {   // ctx[h] += sum_t w[t]*enc[t,h] from bf16 LDS
        float a0 = 0.f, a1 = 0.f, a2 = 0.f, a3 = 0.f;
        #pragma unroll
        for (int t = 0; t < ROWS; t += 4) {
            a0 = fmaf(wlds[t],     bf2f(elds[(t    ) * ESTR + tid]), a0);
            a1 = fmaf(wlds[t + 1], bf2f(elds[(t + 1) * ESTR + tid]), a1);
            a2 = fmaf(wlds[t + 2], bf2f(elds[(t + 2) * ESTR + tid]), a2);
            a3 = fmaf(wlds[t + 3], bf2f(elds[(t + 3) * ESTR + tid]), a3);
        }
        atomicAdd(&ctx_raw[b * H + tid], (a0 + a1) + (a2 + a3));
    }
}

// ---------------- decoder (fused gc prologue + 5 steps), 512 threads ----------------
__global__ __launch_bounds__(512) void decoder2(const float* __restrict__ x,
                                                const float* __restrict__ c0,
                                                const float* __restrict__ ctx_raw,
                                                const float* __restrict__ lsum,
                                                const float* __restrict__ h0,
                                                const float* __restrict__ WihT,
                                                const float* __restrict__ WhhT,
                                                const float* __restrict__ b_ih,
                                                const float* __restrict__ b_hh,
                                                const float* __restrict__ wx,
                                                const float* __restrict__ W1T,
                                                const float* __restrict__ b1,
                                                const float* __restrict__ W2T,
                                                const float* __restrict__ b2,
                                                const float* __restrict__ W3,
                                                const float* __restrict__ b3,
                                                float* __restrict__ out) {
    __shared__ float s_gc[G4];
    __shared__ float s_wx[G4];
    __shared__ float s_ctx[H];
    __shared__ float s_q[H];
    __shared__ float s_out[H];
    __shared__ float s_o1[100];
    __shared__ float s_o2[50];
    __shared__ float s_w3[64];
    __shared__ float s_x;
    int b = blockIdx.x, tid = threadIdx.x;

    if (tid < H) {
        float invl = 1.f / lsum[b];
        s_ctx[tid] = ctx_raw[b * H + tid] * invl;
        s_q[tid]   = h0[b * H + tid];
    }
    s_wx[tid] = wx[tid];
    if (tid < G4 - 512) s_wx[512 + tid] = wx[512 + tid];
    if (tid < 64) s_w3[tid] = (tid < 50) ? W3[tid] : 0.f;
    if (tid == 0) s_x = x[b];
    float b3v = b3[0];
    __syncthreads();

    // gc[j] = b_ih+b_hh + ctx.Wih[:,1:] + q.Whh   (two j per thread)
    {
        int j0 = tid;
        int j1 = 512 + ((tid < 288) ? tid : 287);
        float a0 = b_ih[j0] + b_hh[j0];
        float a1 = b_ih[j1] + b_hh[j1];
        #pragma unroll 4
        for (int k = 0; k < H; k++) {
            float cv = s_ctx[k], qv = s_q[k];
            a0 = fmaf(cv, WihT[k * G4 + j0], a0);
            a0 = fmaf(qv, WhhT[k * G4 + j0], a0);
            a1 = fmaf(cv, WihT[k * G4 + j1], a1);
            a1 = fmaf(qv, WhhT[k * G4 + j1], a1);
        }
        s_gc[j0] = a0;
        if (tid < 288) s_gc[512 + tid] = a1;
    }
    float cprev = (tid < H) ? c0[b * H + tid] : 0.f;
    __syncthreads();

    for (int s = 0; s < 5; s++) {
        float xv = s_x;
        if (tid < H) {
            float ig = s_gc[tid]         + xv * s_wx[tid];
            float fg = s_gc[H + tid]     + xv * s_wx[H + tid];
            float gg = s_gc[2 * H + tid] + xv * s_wx[2 * H + tid];
            float og = s_gc[3 * H + tid] + xv * s_wx[3 * H + tid];
            float c  = sigm(fg) * cprev + sigm(ig) * tanhf(gg);
            float hn = sigm(og) * tanhf(c);
            s_out[tid] = fmaxf(hn, 0.f);
        }
        __syncthreads();
        if (tid < 400) {   // W1: 4 lanes per output, k split 4x50
            int j = tid >> 2, q4 = tid & 3;
            float a = 0.f;
            const float* wp = W1T + (q4 * 50) * 100 + j;
            const float* op = s_out + q4 * 50;
            #pragma unroll 10
            for (int k = 0; k < 50; k++) a = fmaf(wp[k * 100], op[k], a);
            a += __shfl_xor(a, 1);
            a += __shfl_xor(a, 2);
            if (q4 == 0) s_o1[j] = fmaxf(a + b1[j], 0.f);
        }
        __syncthreads();
        if (tid < 200) {   // W2: 4 lanes per output, k split 4x25
            int j = tid >> 2, q4 = tid & 3;
            float a = 0.f;
            const float* wp = W2T + (q4 * 25) * 50 + j;
            const float* op = s_o1 + q4 * 25;
            #pragma unroll 5
            for (int k = 0; k < 25; k++) a = fmaf(wp[k * 50], op[k], a);
            a += __shfl_xor(a, 1);
            a += __shfl_xor(a, 2);
            if (q4 == 0) s_o2[j] = fmaxf(a + b2[j], 0.f);
        }
        __syncthreads();
        if (tid < 64) {   // W3: wave reduce
            float a = (tid < 50) ? s_w3[tid] * s_o2[tid] : 0.f;
            #pragma unroll
            for (int d = 1; d < 64; d <<= 1) a += __shfl_xor(a, d);
            if (tid == 0) {
                float y = a + b3v;
                out[b * 5 + s] = y;
                s_x = y;
            }
        }
        __syncthreads();
    }
}

// ---------------- launch ----------------
extern "C" void kernel_launch(void* const* d_in, const int* in_sizes, int n_in,
                              void* d_out, int out_size, void* d_ws, size_t ws_size,
                              hipStream_t stream) {
    (void)in_sizes; (void)n_in; (void)out_size; (void)ws_size;
    const float* x    = (const float*)d_in[0];
    const float* h0   = (const float*)d_in[1];
    const float* c0   = (const float*)d_in[2];
    const float* enc  = (const float*)d_in[3];
    const float* Wa   = (const float*)d_in[4];
    const float* ba   = (const float*)d_in[5];
    const float* Ua   = (const float*)d_in[6];
    const float* bua  = (const float*)d_in[7];
    const float* Va   = (const float*)d_in[8];
    const float* bva  = (const float*)d_in[9];
    const float* W_ih = (const float*)d_in[10];
    const float* W_hh = (const float*)d_in[11];
    const float* b_ih = (const float*)d_in[12];
    const float* b_hh = (const float*)d_in[13];
    const float* W1   = (const float*)d_in[14];
    const float* b1   = (const float*)d_in[15];
    const float* W2   = (const float*)d_in[16];
    const float* b2   = (const float*)d_in[17];
    const float* W3   = (const float*)d_in[18];
    const float* b3   = (const float*)d_in[19];
    float* out = (float*)d_out;

    char* ws = (char*)d_ws;
    unsigned short* Uab = (unsigned short*)(ws);   // 114688
    float* WihT    = (float*)(ws + 114688);        // 640000
    float* WhhT    = (float*)(ws + 754688);        // 640000
    float* wx      = (float*)(ws + 1394688);       // 3200
    float* qb      = (float*)(ws + 1397888);       // 102400
    float* W1T     = (float*)(ws + 1500288);       // 80000
    float* W2T     = (float*)(ws + 1580288);       // 20000
    float* ctx_raw = (float*)(ws + 1600288);       // 102400
    float* lsum    = (float*)(ws + 1702688);       // 512

    hipMemsetAsync(ws + 1600288, 0, 102912, stream);   // ctx_raw + lsum
    prep_all<<<dim3(1085), 256, 0, stream>>>(Ua, Wa, ba, bua, h0, W_ih, W_hh, W1, W2,
                                             Uab, WihT, WhhT, wx, qb, W1T, W2T);
    scores_ctx<<<dim3(8192), 256, 0, stream>>>(enc, Uab, qb, Va, bva, ctx_raw, lsum);
    decoder2<<<dim3(B), 512, 0, stream>>>(x, c0, ctx_raw, lsum, h0, WihT, WhhT,
                                          b_ih, b_hh, wx, W1T, b1, W2T, b2, W3, b3, out);
}

// Round 8
// 172.566 us; speedup vs baseline: 2.0851x; 1.0114x over previous
//
#include <hip/hip_runtime.h>
#include <math.h>

#define B 128
#define T 2048
#define H 200
#define G4 800    // 4*H
#define KP 224    // Uab row stride (bf16)
#define ESTR 208  // elds row stride (bf16): 200 data + 8 pad (zeroed)
#define ROWS 32   // t-rows per block

typedef short short8 __attribute__((ext_vector_type(8)));
typedef float floatx4 __attribute__((ext_vector_type(4)));

__device__ __forceinline__ unsigned short f2bf(float x) {
    unsigned u = __float_as_uint(x);
    return (unsigned short)((u + 0x7fffu + ((u >> 16) & 1u)) >> 16);
}
__device__ __forceinline__ float bf2f(unsigned short s) {
    return __uint_as_float(((unsigned)s) << 16);
}
// pack two floats -> two bf16 (round-nearest-away) in 3 VALU ops
__device__ __forceinline__ unsigned pk2(float a, float b) {
    return __builtin_amdgcn_perm(__float_as_uint(b) + 0x8000u,
                                 __float_as_uint(a) + 0x8000u, 0x07060302u);
}
// tanh(x) = 1 - 2/(exp(2x)+1), hw exp2 + rcp (~1e-6 rel err)
__device__ __forceinline__ float ftanh(float x) {
    float e = __builtin_amdgcn_exp2f(x * 2.885390081777927f);
    float r = __builtin_amdgcn_rcpf(e + 1.f);
    return fmaf(-2.f, r, 1.f);
}
__device__ __forceinline__ float sigm(float x) { return 1.f / (1.f + expf(-x)); }

// ---------------- prep_all ----------------
// blocks 0..255    : Uab row (bf16, zero-padded [256][224])
// blocks 256..455  : W_ihT[k][j] = W_ih[j][1+k]
// blocks 456..655  : W_hhT[k][j] = W_hh[j][k]
// block  656       : wx[j] = W_ih[j][0]
// blocks 657..784  : qb[b][h] = h0[b] @ Wa.T + ba + bua   (float4 dot)
// blocks 785..984  : W1T[k][j] = W1[j][k]   (k<200, j<100)
// blocks 985..1084 : W2T[k][j] = W2[j][k]   (k<100, j<50)
__global__ __launch_bounds__(256) void prep_all(const float* __restrict__ Ua,
                                                const float* __restrict__ Wa,
                                                const float* __restrict__ ba,
                                                const float* __restrict__ bua,
                                                const float* __restrict__ h0,
                                                const float* __restrict__ W_ih,
                                                const float* __restrict__ W_hh,
                                                const float* __restrict__ W1,
                                                const float* __restrict__ W2,
                                                unsigned short* __restrict__ Uab,
                                                float* __restrict__ WihT,
                                                float* __restrict__ WhhT,
                                                float* __restrict__ wx,
                                                float* __restrict__ qb,
                                                float* __restrict__ W1T,
                                                float* __restrict__ W2T) {
    __shared__ __align__(16) float qs[H];
    int bx = blockIdx.x, tid = threadIdx.x;
    if (bx < 256) {
        if (tid < KP) {
            float v = (bx < H && tid < H) ? Ua[bx * H + tid] : 0.f;
            Uab[bx * KP + tid] = f2bf(v);
        }
    } else if (bx < 456) {
        int k = bx - 256;
        for (int j = tid; j < G4; j += 256) WihT[k * G4 + j] = W_ih[(size_t)j * (H + 1) + 1 + k];
    } else if (bx < 656) {
        int k = bx - 456;
        for (int j = tid; j < G4; j += 256) WhhT[k * G4 + j] = W_hh[(size_t)j * H + k];
    } else if (bx == 656) {
        for (int j = tid; j < G4; j += 256) wx[j] = W_ih[(size_t)j * (H + 1)];
    } else if (bx < 785) {
        int b = bx - 657;
        if (tid < H) qs[tid] = h0[b * H + tid];
        __syncthreads();
        if (tid < H) {
            float a = ba[tid] + bua[tid];
            const float4* w  = (const float4*)(Wa + tid * H);
            const float4* qv = (const float4*)qs;
            #pragma unroll 8
            for (int k = 0; k < 50; k++) {
                float4 wv = w[k], q4 = qv[k];
                a = fmaf(wv.x, q4.x, a);
                a = fmaf(wv.y, q4.y, a);
                a = fmaf(wv.z, q4.z, a);
                a = fmaf(wv.w, q4.w, a);
            }
            qb[b * H + tid] = a;
        }
    } else if (bx < 985) {
        int k = bx - 785;
        if (tid < 100) W1T[k * 100 + tid] = W1[tid * H + k];
    } else {
        int k = bx - 985;
        if (tid < 50) W2T[k * 50 + tid] = W2[tid * 100 + k];
    }
}

// ---------------- scores + bounded-softmax + context ----------------
// Grid: 8192 = (b, 1/64 of T), 32 rows each. Reg-stage -> bf16 LDS, staging split
// into two low-liveness halves (peak ~16 VGPR) with a sched_barrier so the
// compiler can't hoist half-2 loads into half-1 (R7: hoisting at a 64-reg budget
// spilled 65 MB/dispatch). launch_bounds(256,6): ~85 VGPR budget fits migscore<2>'s
// 56-reg af block (R5 evidence), 24 waves/CU. k>=200 annihilated by Uab's zero
// columns -> uniform 7-iter ks loop. 13 m-tiles split {4,3,3,3} across waves.

template<int NM>
__device__ __forceinline__ void migscore(const unsigned short* __restrict__ Uab,
                                         const unsigned short* elds,
                                         const float* s_va, const float* s_qb,
                                         int m0, int r, int q, float p[2]) {
    short8 af[NM][7];
    #pragma unroll
    for (int m = 0; m < NM; m++)
        #pragma unroll
        for (int ks = 0; ks < 7; ks++)
            af[m][ks] = *(const short8*)(Uab + ((m0 + m) * 16 + r) * KP + ks * 32 + q * 8);
    #pragma unroll
    for (int nt = 0; nt < 2; nt++) {
        const unsigned short* rowp = elds + (nt * 16 + r) * ESTR;
        floatx4 C[NM];
        #pragma unroll
        for (int m = 0; m < NM; m++) C[m] = (floatx4){0.f, 0.f, 0.f, 0.f};
        #pragma unroll
        for (int ks = 0; ks < 7; ks++) {
            short8 bf = *(const short8*)(rowp + ks * 32 + q * 8);
            #pragma unroll
            for (int m = 0; m < NM; m++)
                C[m] = __builtin_amdgcn_mfma_f32_16x16x32_bf16(af[m][ks], bf, C[m], 0, 0, 0);
        }
        float pp = 0.f;
        #pragma unroll
        for (int m = 0; m < NM; m++)
            #pragma unroll
            for (int g = 0; g < 4; g++) {
                int h = (m0 + m) * 16 + q * 4 + g;
                pp += s_va[h] * ftanh(s_qb[h] + C[m][g]);
            }
        p[nt] += pp;
    }
}

__device__ __forceinline__ void stg(unsigned short* elds, int f, float4 v) {
    int row = f / 50, c4 = f - row * 50;
    uint2 wv;
    wv.x = pk2(v.x, v.y);
    wv.y = pk2(v.z, v.w);
    *(uint2*)&elds[row * ESTR + c4 * 4] = wv;
}

__global__ __launch_bounds__(256, 6) void scores_ctx(const float* __restrict__ enc,
                                                     const unsigned short* __restrict__ Uab,
                                                     const float* __restrict__ qb,
                                                     const float* __restrict__ Va,
                                                     const float* __restrict__ bva,
                                                     float* __restrict__ ctx_raw,
                                                     float* __restrict__ lsum) {
    __shared__ unsigned short elds[ROWS * ESTR + 32];   // 13376 B (incl 64 B tail pad)
    __shared__ float s_qb[ESTR];                        // 832 B (cols 200..207 zero)
    __shared__ float s_va[ESTR];                        // 832 B
    __shared__ float part[4][ROWS];                     // 512 B
    __shared__ float wlds[ROWS];                        // 128 B

    int bx  = blockIdx.x;
    int b   = bx >> 6;
    int t0  = (bx & 63) * ROWS;
    int tid = threadIdx.x, w = tid >> 6, lane = tid & 63, r = lane & 15, q = lane >> 4;

    const float4* gsrc = (const float4*)(enc + (size_t)(b * T + t0) * H);

    // ---- staging half 1: 3 float4 in flight (12 VGPR) ----
    float4 a0 = gsrc[tid];
    float4 a1 = gsrc[tid + 256];
    float4 a2 = gsrc[tid + 512];

    // independent setup while half-1 loads fly
    if (tid < 200) { s_qb[tid] = qb[b * H + tid]; s_va[tid] = Va[tid]; }
    else if (tid < 208) { s_qb[tid] = 0.f; s_va[tid] = 0.f; }
    float bv = bva[0];

    // zero elds pad: cols 200..207 of each row + 32-short tail (NaN*0 guard)
    if (tid < 128) {
        int row = tid >> 2, pr = tid & 3;
        *(unsigned*)&elds[row * ESTR + 200 + pr * 2] = 0u;
    } else if (tid < 144) {
        *(unsigned*)&elds[ROWS * ESTR + (tid - 128) * 2] = 0u;
    }

    stg(elds, tid,       a0);
    stg(elds, tid + 256, a1);
    stg(elds, tid + 512, a2);
    __builtin_amdgcn_sched_barrier(0);   // keep half-2 loads from hoisting into half-1

    // ---- staging half 2: 4 float4 in flight (16 VGPR) ----
    float4 b0 = gsrc[tid + 768];
    float4 b1 = gsrc[tid + 1024];
    float4 b2 = gsrc[tid + 1280];
    float4 b3;
    if (tid < 64) b3 = gsrc[tid + 1536];
    stg(elds, tid + 768,  b0);
    stg(elds, tid + 1024, b1);
    stg(elds, tid + 1280, b2);
    if (tid < 64) stg(elds, tid + 1536, b3);
    __syncthreads();

    // scores: 13 m-tiles {0-3},{4-6},{7-9},{10-12}
    float p[2] = {0.f, 0.f};
    if (w == 0) {
        migscore<2>(Uab, elds, s_va, s_qb, 0, r, q, p);
        migscore<2>(Uab, elds, s_va, s_qb, 2, r, q, p);
    } else {
        int mb = 1 + 3 * w;
        migscore<2>(Uab, elds, s_va, s_qb, mb, r, q, p);
        migscore<1>(Uab, elds, s_va, s_qb, mb + 2, r, q, p);
    }
    #pragma unroll
    for (int nt = 0; nt < 2; nt++) {
        float pp = p[nt];
        pp += __shfl_xor(pp, 16);
        pp += __shfl_xor(pp, 32);
        if (q == 0) part[w][nt * 16 + r] = pp;
    }
    __syncthreads();

    if (w == 0) {   // wave 0: bound + softmax + lsum atomic
        float a = fabsf(s_va[lane]) + fabsf(s_va[lane + 64]) + fabsf(s_va[lane + 128]);
        if (lane < 16) a += fabsf(s_va[lane + 192]);
        #pragma unroll
        for (int d = 1; d < 64; d <<= 1) a += __shfl_xor(a, d);
        float bound = a + fabsf(bv);

        float we = 0.f;
        if (lane < ROWS) {
            float s = part[0][lane] + part[1][lane] + part[2][lane] + part[3][lane] + bv;
            we = __builtin_amdgcn_exp2f((s - bound) * 1.4426950408889634f);
            wlds[lane] = we;
        }
        #pragma unroll
        for (int d = 1; d < 64; d <<= 1) we += __shfl_xor(we, d);
        if (lane == 0) atomicAdd(&lsum[b], we);
    }
    __syncthreads();

    if (tid < H) {   // ctx[h] += sum_t w[t]*enc[t,h] from bf16 LDS
        float a0c = 0.f, a1c = 0.f, a2c = 0.f, a3c = 0.f;
        #pragma unroll
        for (int t = 0; t < ROWS; t += 4) {
            a0c = fmaf(wlds[t],     bf2f(elds[(t    ) * ESTR + tid]), a0c);
            a1c = fmaf(wlds[t + 1], bf2f(elds[(t + 1) * ESTR + tid]), a1c);
            a2c = fmaf(wlds[t + 2], bf2f(elds[(t + 2) * ESTR + tid]), a2c);
            a3c = fmaf(wlds[t + 3], bf2f(elds[(t + 3) * ESTR + tid]), a3c);
        }
        atomicAdd(&ctx_raw[b * H + tid], (a0c + a1c) + (a2c + a3c));
    }
}

// ---------------- decoder (fused gc prologue + 5 steps), 512 threads ----------------
__global__ __launch_bounds__(512) void decoder2(const float* __restrict__ x,
                                                const float* __restrict__ c0,
                                                const float* __restrict__ ctx_raw,
                                                const float* __restrict__ lsum,
                                                const float* __restrict__ h0,
                                                const float* __restrict__ WihT,
                                                const float* __restrict__ WhhT,
                                                const float* __restrict__ b_ih,
                                                const float* __restrict__ b_hh,
                                                const float* __restrict__ wx,
                                                const float* __restrict__ W1T,
                                                const float* __restrict__ b1,
                                                const float* __restrict__ W2T,
                                                const float* __restrict__ b2,
                                                const float* __restrict__ W3,
                                                const float* __restrict__ b3,
                                                float* __restrict__ out) {
    __shared__ float s_gc[G4];
    __shared__ float s_wx[G4];
    __shared__ float s_ctx[H];
    __shared__ float s_q[H];
    __shared__ float s_out[H];
    __shared__ float s_o1[100];
    __shared__ float s_o2[50];
    __shared__ float s_w3[64];
    __shared__ float s_x;
    int b = blockIdx.x, tid = threadIdx.x;

    if (tid < H) {
        float invl = 1.f / lsum[b];
        s_ctx[tid] = ctx_raw[b * H + tid] * invl;
        s_q[tid]   = h0[b * H + tid];
    }
    s_wx[tid] = wx[tid];
    if (tid < G4 - 512) s_wx[512 + tid] = wx[512 + tid];
    if (tid < 64) s_w3[tid] = (tid < 50) ? W3[tid] : 0.f;
    if (tid == 0) s_x = x[b];
    float b3v = b3[0];
    __syncthreads();

    // gc[j] = b_ih+b_hh + ctx.Wih[:,1:] + q.Whh   (two j per thread)
    {
        int j0 = tid;
        int j1 = 512 + ((tid < 288) ? tid : 287);
        float a0 = b_ih[j0] + b_hh[j0];
        float a1 = b_ih[j1] + b_hh[j1];
        #pragma unroll 4
        for (int k = 0; k < H; k++) {
            float cv = s_ctx[k], qv = s_q[k];
            a0 = fmaf(cv, WihT[k * G4 + j0], a0);
            a0 = fmaf(qv, WhhT[k * G4 + j0], a0);
            a1 = fmaf(cv, WihT[k * G4 + j1], a1);
            a1 = fmaf(qv, WhhT[k * G4 + j1], a1);
        }
        s_gc[j0] = a0;
        if (tid < 288) s_gc[512 + tid] = a1;
    }
    float cprev = (tid < H) ? c0[b * H + tid] : 0.f;
    __syncthreads();

    for (int s = 0; s < 5; s++) {
        float xv = s_x;
        if (tid < H) {
            float ig = s_gc[tid]         + xv * s_wx[tid];
            float fg = s_gc[H + tid]     + xv * s_wx[H + tid];
            float gg = s_gc[2 * H + tid] + xv * s_wx[2 * H + tid];
            float og = s_gc[3 * H + tid] + xv * s_wx[3 * H + tid];
            float c  = sigm(fg) * cprev + sigm(ig) * tanhf(gg);
            float hn = sigm(og) * tanhf(c);
            s_out[tid] = fmaxf(hn, 0.f);
        }
        __syncthreads();
        if (tid < 400) {   // W1: 4 lanes per output, k split 4x50
            int j = tid >> 2, q4 = tid & 3;
            float a = 0.f;
            const float* wp = W1T + (q4 * 50) * 100 + j;
            const float* op = s_out + q4 * 50;
            #pragma unroll 10
            for (int k = 0; k < 50; k++) a = fmaf(wp[k * 100], op[k], a);
            a += __shfl_xor(a, 1);
            a += __shfl_xor(a, 2);
            if (q4 == 0) s_o1[j] = fmaxf(a + b1[j], 0.f);
        }
        __syncthreads();
        if (tid < 200) {   // W2: 4 lanes per output, k split 4x25
            int j = tid >> 2, q4 = tid & 3;
            float a = 0.f;
            const float* wp = W2T + (q4 * 25) * 50 + j;
            const float* op = s_o1 + q4 * 25;
            #pragma unroll 5
            for (int k = 0; k < 25; k++) a = fmaf(wp[k * 50], op[k], a);
            a += __shfl_xor(a, 1);
            a += __shfl_xor(a, 2);
            if (q4 == 0) s_o2[j] = fmaxf(a + b2[j], 0.f);
        }
        __syncthreads();
        if (tid < 64) {   // W3: wave reduce
            float a = (tid < 50) ? s_w3[tid] * s_o2[tid] : 0.f;
            #pragma unroll
            for (int d = 1; d < 64; d <<= 1) a += __shfl_xor(a, d);
            if (tid == 0) {
                float y = a + b3v;
                out[b * 5 + s] = y;
                s_x = y;
            }
        }
        __syncthreads();
    }
}

// ---------------- launch ----------------
extern "C" void kernel_launch(void* const* d_in, const int* in_sizes, int n_in,
                              void* d_out, int out_size, void* d_ws, size_t ws_size,
                              hipStream_t stream) {
    (void)in_sizes; (void)n_in; (void)out_size; (void)ws_size;
    const float* x    = (const float*)d_in[0];
    const float* h0   = (const float*)d_in[1];
    const float* c0   = (const float*)d_in[2];
    const float* enc  = (const float*)d_in[3];
    const float* Wa   = (const float*)d_in[4];
    const float* ba   = (const float*)d_in[5];
    const float* Ua   = (const float*)d_in[6];
    const float* bua  = (const float*)d_in[7];
    const float* Va   = (const float*)d_in[8];
    const float* bva  = (const float*)d_in[9];
    const float* W_ih = (const float*)d_in[10];
    const float* W_hh = (const float*)d_in[11];
    const float* b_ih = (const float*)d_in[12];
    const float* b_hh = (const float*)d_in[13];
    const float* W1   = (const float*)d_in[14];
    const float* b1   = (const float*)d_in[15];
    const float* W2   = (const float*)d_in[16];
    const float* b2   = (const float*)d_in[17];
    const float* W3   = (const float*)d_in[18];
    const float* b3   = (const float*)d_in[19];
    float* out = (float*)d_out;

    char* ws = (char*)d_ws;
    unsigned short* Uab = (unsigned short*)(ws);   // 114688
    float* WihT    = (float*)(ws + 114688);        // 640000
    float* WhhT    = (float*)(ws + 754688);        // 640000
    float* wx      = (float*)(ws + 1394688);       // 3200
    float* qb      = (float*)(ws + 1397888);       // 102400
    float* W1T     = (float*)(ws + 1500288);       // 80000
    float* W2T     = (float*)(ws + 1580288);       // 20000
    float* ctx_raw = (float*)(ws + 1600288);       // 102400
    float* lsum    = (float*)(ws + 1702688);       // 512

    hipMemsetAsync(ws + 1600288, 0, 102912, stream);   // ctx_raw + lsum
    prep_all<<<dim3(1085), 256, 0, stream>>>(Ua, Wa, ba, bua, h0, W_ih, W_hh, W1, W2,
                                             Uab, WihT, WhhT, wx, qb, W1T, W2T);
    scores_ctx<<<dim3(8192), 256, 0, stream>>>(enc, Uab, qb, Va, bva, ctx_raw, lsum);
    decoder2<<<dim3(B), 512, 0, stream>>>(x, c0, ctx_raw, lsum, h0, WihT, WhhT,
                                          b_ih, b_hh, wx, W1T, b1, W2T, b2, W3, b3, out);
}